// Round 1
// baseline (98.691 us; speedup 1.0000x reference)
//
#include <hip/hip_runtime.h>

#define NB 32
#define NN 64
#define ND 128
#define NH 256
#define LN_EPS 1e-5f

__device__ __forceinline__ float gelu_exact(float x) {
    return 0.5f * x * (1.0f + erff(x * 0.70710678118654752440f));
}

// Kernel 1: Pt[row,h] = sum_d slots[row,d]*We1[d,h] + be1[h]
//           Qm[row,h] = sum_d slots[row,d]*We1[D+d,h]
__global__ __launch_bounds__(NH) void k_pq(const float* __restrict__ slots,
                                           const float* __restrict__ We1,
                                           const float* __restrict__ be1,
                                           float* __restrict__ Pt,
                                           float* __restrict__ Qm) {
    __shared__ float xs[ND];
    const int row = blockIdx.x;
    const int t = threadIdx.x;
    if (t < ND) xs[t] = slots[row * ND + t];
    __syncthreads();
    float pt = be1[t];
    float q = 0.0f;
    const float* w1 = We1 + t;
    #pragma unroll 8
    for (int d = 0; d < ND; ++d) {
        const float x = xs[d];
        pt = fmaf(x, w1[d * NH], pt);
        q  = fmaf(x, w1[(ND + d) * NH], q);
    }
    Pt[row * NH + t] = pt;
    Qm[row * NH + t] = q;
}

// Kernel 2: per (b,i) block: s = sum_j w_j * gelu(LN(Pt_i + Q_j)),
// messages = s @ We2 + wsum*be2, node MLP, out = slots + delta.
__global__ __launch_bounds__(NH) void k_main(
    const float* __restrict__ slots,
    const float* __restrict__ adj,
    const float* __restrict__ Pt,
    const float* __restrict__ Qm,
    const float* __restrict__ ge,  const float* __restrict__ bge,
    const float* __restrict__ We2, const float* __restrict__ be2,
    const float* __restrict__ Wn1, const float* __restrict__ bn1,
    const float* __restrict__ gn,  const float* __restrict__ bgn,
    const float* __restrict__ Wn2, const float* __restrict__ bn2,
    float* __restrict__ out)
{
    __shared__ float lds_pt[NH];
    __shared__ float lds_w[NN];
    __shared__ float lds_x[ND];
    __shared__ float lds_s[4][NH];
    __shared__ float lds_sf[NH];
    __shared__ float lds_nin[2 * ND];
    __shared__ float lds_g1[NH];
    __shared__ float lds_red[8];

    const int row  = blockIdx.x;       // b*N + i
    const int bidx = row >> 6;
    const int i    = row & 63;
    const int t    = threadIdx.x;
    const int lane = t & 63;
    const int wave = t >> 6;

    // ---- load row data ----
    lds_pt[t] = Pt[row * NH + t];
    if (t < NN) {
        const float a = adj[row * NN + t];
        lds_w[t] = (t == i) ? 0.0f : a;
    }
    if (t < ND) lds_x[t] = slots[row * ND + t];
    __syncthreads();

    // ---- phase B: per-wave j loop; lane owns channels 4*lane..4*lane+3 ----
    const float4 p4 = reinterpret_cast<const float4*>(lds_pt)[lane];
    const float4 g4 = reinterpret_cast<const float4*>(ge)[lane];
    const float4 b4 = reinterpret_cast<const float4*>(bge)[lane];
    const float4* Qb = reinterpret_cast<const float4*>(Qm + (size_t)bidx * NN * NH);
    float4 sacc = make_float4(0.f, 0.f, 0.f, 0.f);

    for (int j = wave; j < NN; j += 4) {
        const float wj = lds_w[j];
        if (wj == 0.0f) continue;               // wave-uniform (diagonal)
        const float4 q4 = Qb[j * (NH / 4) + lane];
        const float hx = p4.x + q4.x;
        const float hy = p4.y + q4.y;
        const float hz = p4.z + q4.z;
        const float hw = p4.w + q4.w;
        float s1 = (hx + hy) + (hz + hw);
        float s2 = fmaf(hx, hx, fmaf(hy, hy, fmaf(hz, hz, hw * hw)));
        #pragma unroll
        for (int off = 32; off > 0; off >>= 1) {
            s1 += __shfl_xor(s1, off, 64);
            s2 += __shfl_xor(s2, off, 64);
        }
        const float mu  = s1 * (1.0f / NH);
        const float var = s2 * (1.0f / NH) - mu * mu;
        const float rr  = rsqrtf(var + LN_EPS);
        const float y0 = gelu_exact(fmaf((hx - mu) * rr, g4.x, b4.x));
        const float y1 = gelu_exact(fmaf((hy - mu) * rr, g4.y, b4.y));
        const float y2 = gelu_exact(fmaf((hz - mu) * rr, g4.z, b4.z));
        const float y3 = gelu_exact(fmaf((hw - mu) * rr, g4.w, b4.w));
        sacc.x = fmaf(wj, y0, sacc.x);
        sacc.y = fmaf(wj, y1, sacc.y);
        sacc.z = fmaf(wj, y2, sacc.z);
        sacc.w = fmaf(wj, y3, sacc.w);
    }

    // ---- phase C: combine s across waves ----
    reinterpret_cast<float4*>(lds_s[wave])[lane] = sacc;
    __syncthreads();
    lds_sf[t] = (lds_s[0][t] + lds_s[1][t]) + (lds_s[2][t] + lds_s[3][t]);
    float wsum = 0.0f;
    for (int j = 0; j < NN; ++j) wsum += lds_w[j];
    __syncthreads();

    // ---- phase D: messages = s @ We2 + wsum*be2; build node input ----
    if (t < ND) {
        float m = wsum * be2[t];
        const float* w2 = We2 + t;
        #pragma unroll 8
        for (int k = 0; k < NH; ++k) m = fmaf(lds_sf[k], w2[k * ND], m);
        lds_nin[t]      = lds_x[t];
        lds_nin[ND + t] = m;
    }
    __syncthreads();

    // ---- phase E: h1 = node_in @ Wn1 + bn1; LN; GELU ----
    float h1 = bn1[t];
    {
        const float* wn1 = Wn1 + t;
        #pragma unroll 8
        for (int k = 0; k < 2 * ND; ++k) h1 = fmaf(lds_nin[k], wn1[k * NH], h1);
    }
    float r1 = h1, r2 = h1 * h1;
    #pragma unroll
    for (int off = 32; off > 0; off >>= 1) {
        r1 += __shfl_xor(r1, off, 64);
        r2 += __shfl_xor(r2, off, 64);
    }
    if (lane == 0) { lds_red[wave] = r1; lds_red[4 + wave] = r2; }
    __syncthreads();
    {
        const float S1 = (lds_red[0] + lds_red[1]) + (lds_red[2] + lds_red[3]);
        const float S2 = (lds_red[4] + lds_red[5]) + (lds_red[6] + lds_red[7]);
        const float mu  = S1 * (1.0f / NH);
        const float var = S2 * (1.0f / NH) - mu * mu;
        const float rr  = rsqrtf(var + LN_EPS);
        const float y   = (h1 - mu) * rr;
        lds_g1[t] = gelu_exact(fmaf(y, gn[t], bgn[t]));
    }
    __syncthreads();

    // ---- phase F: delta = g1 @ Wn2 + bn2; out = slots + delta ----
    if (t < ND) {
        float dlt = bn2[t];
        const float* wn2 = Wn2 + t;
        #pragma unroll 8
        for (int k = 0; k < NH; ++k) dlt = fmaf(lds_g1[k], wn2[k * ND], dlt);
        out[row * ND + t] = lds_x[t] + dlt;
    }
}

extern "C" void kernel_launch(void* const* d_in, const int* in_sizes, int n_in,
                              void* d_out, int out_size, void* d_ws, size_t ws_size,
                              hipStream_t stream) {
    const float* slots = (const float*)d_in[0];
    const float* adj   = (const float*)d_in[1];
    const float* We1   = (const float*)d_in[2];
    const float* be1   = (const float*)d_in[3];
    const float* ge    = (const float*)d_in[4];
    const float* bge   = (const float*)d_in[5];
    const float* We2   = (const float*)d_in[6];
    const float* be2   = (const float*)d_in[7];
    const float* Wn1   = (const float*)d_in[8];
    const float* bn1   = (const float*)d_in[9];
    const float* gn    = (const float*)d_in[10];
    const float* bgn   = (const float*)d_in[11];
    const float* Wn2   = (const float*)d_in[12];
    const float* bn2   = (const float*)d_in[13];
    float* out = (float*)d_out;

    float* Ptw = (float*)d_ws;                 // [2048, 256]
    float* Qw  = Ptw + (size_t)NB * NN * NH;   // [2048, 256]

    k_pq<<<NB * NN, NH, 0, stream>>>(slots, We1, be1, Ptw, Qw);
    k_main<<<NB * NN, NH, 0, stream>>>(slots, adj, Ptw, Qw, ge, bge, We2, be2,
                                       Wn1, bn1, gn, bgn, Wn2, bn2, out);
}

// Round 2
// 79.863 us; speedup vs baseline: 1.2357x; 1.2357x over previous
//
#include <hip/hip_runtime.h>

#define NB 32
#define NN 64
#define ND 128
#define NH 256
#define LN_EPS 1e-5f

// Branchless erf-based exact GELU: Abramowitz-Stegun 7.1.26, |err(erf)| <= 1.5e-7
__device__ __forceinline__ float gelu_fast(float x) {
    const float z  = fabsf(x) * 0.70710678118654752440f;
    const float t  = __builtin_amdgcn_rcpf(fmaf(0.3275911f, z, 1.0f));
    float p = fmaf(1.061405429f, t, -1.453152027f);
    p = fmaf(p, t, 1.421413741f);
    p = fmaf(p, t, -0.284496736f);
    p = fmaf(p, t, 0.254829592f);
    p = p * t;
    const float e  = __expf(-z * z);
    const float ea = fmaf(-p, e, 1.0f);           // erf(|x|/sqrt2) in [0,1]
    const float er = copysignf(ea, x);
    return 0.5f * x * (1.0f + er);
}

// ---------------- K1: Pt = slots@We1_top + be1 ; Qm = slots@We1_bot ----------------
// 8 rows per block -> We1 (256KB) read once per 8 rows instead of per row.
#define RP 8
__global__ __launch_bounds__(256) void k_pq(const float* __restrict__ slots,
                                            const float* __restrict__ We1,
                                            const float* __restrict__ be1,
                                            float* __restrict__ Pt,
                                            float* __restrict__ Qm) {
    __shared__ float xs[RP][ND];
    const int r0 = blockIdx.x * RP;
    const int t = threadIdx.x;
    #pragma unroll
    for (int r = 0; r < RP; r += 2) {
        const int rr = r + (t >> 7);
        xs[rr][t & 127] = slots[(size_t)(r0 + rr) * ND + (t & 127)];
    }
    __syncthreads();
    float pt[RP], qq[RP];
    const float bb = be1[t];
    #pragma unroll
    for (int r = 0; r < RP; ++r) { pt[r] = bb; qq[r] = 0.0f; }
    for (int d = 0; d < ND; ++d) {
        const float wt  = We1[d * NH + t];
        const float wbt = We1[(ND + d) * NH + t];
        #pragma unroll
        for (int r = 0; r < RP; ++r) {
            const float x = xs[r][d];
            pt[r] = fmaf(x, wt,  pt[r]);
            qq[r] = fmaf(x, wbt, qq[r]);
        }
    }
    #pragma unroll
    for (int r = 0; r < RP; ++r) {
        Pt[(size_t)(r0 + r) * NH + t] = pt[r];
        Qm[(size_t)(r0 + r) * NH + t] = qq[r];
    }
}

// ---------------- K2: S[row] = sum_j w_j * gelu(LN(P_i + Q_j)) ----------------
// 2 receiver rows per block (shared Q reads). LN stats via linearity:
// mu = (SP1 + SQ1)/H ; E[h^2] = (SP2 + 2*P.Q + SQ2)/H ; var = E[h^2]-mu^2.
#define IBLK 2
__global__ __launch_bounds__(256) void k_msg(
    const float* __restrict__ adj,
    const float* __restrict__ Pt,
    const float* __restrict__ Qm,
    const float* __restrict__ ge,  const float* __restrict__ bge,
    float* __restrict__ Sw, float* __restrict__ wsumw)
{
    __shared__ float lds_pt[IBLK][NH];
    __shared__ float lds_w[IBLK][NN];
    __shared__ float lds_mu[IBLK][NN];
    __shared__ float lds_rr[IBLK][NN];
    __shared__ float lds_s[4][IBLK][NH];
    __shared__ float lds_red[16];

    const int blk = blockIdx.x;
    const int b   = blk >> 5;
    const int i0  = (blk & 31) * IBLK;
    const int r0  = b * NN + i0;
    const int t   = threadIdx.x;
    const int lane = t & 63;
    const int wave = t >> 6;

    lds_pt[0][t] = Pt[(size_t)r0 * NH + t];
    lds_pt[1][t] = Pt[(size_t)(r0 + 1) * NH + t];
    if (t < NN) {
        const float a0 = adj[(size_t)r0 * NN + t];
        const float a1 = adj[(size_t)(r0 + 1) * NN + t];
        lds_w[0][t] = (t == i0)     ? 0.0f : a0;
        lds_w[1][t] = (t == i0 + 1) ? 0.0f : a1;
    }
    __syncthreads();

    // block sums of P and P^2 for both rows
    {
        const float p0 = lds_pt[0][t], p1 = lds_pt[1][t];
        float a0 = p0, b0 = p0 * p0, a1 = p1, b1 = p1 * p1;
        #pragma unroll
        for (int off = 32; off; off >>= 1) {
            a0 += __shfl_xor(a0, off); b0 += __shfl_xor(b0, off);
            a1 += __shfl_xor(a1, off); b1 += __shfl_xor(b1, off);
        }
        if (lane == 0) {
            lds_red[wave] = a0; lds_red[4 + wave] = b0;
            lds_red[8 + wave] = a1; lds_red[12 + wave] = b1;
        }
    }
    __syncthreads();
    const float SP1_0 = (lds_red[0] + lds_red[1]) + (lds_red[2] + lds_red[3]);
    const float SP2_0 = (lds_red[4] + lds_red[5]) + (lds_red[6] + lds_red[7]);
    const float SP1_1 = (lds_red[8] + lds_red[9]) + (lds_red[10] + lds_red[11]);
    const float SP2_1 = (lds_red[12] + lds_red[13]) + (lds_red[14] + lds_red[15]);

    // C-dot prologue: j = t>>2, part = t&3 each covers 64 channels
    {
        const int j = t >> 2, part = t & 3;
        const float4* qrow  = (const float4*)(Qm + ((size_t)b * NN + j) * NH);
        const float4* prow0 = (const float4*)lds_pt[0];
        const float4* prow1 = (const float4*)lds_pt[1];
        float cd0 = 0.f, cd1 = 0.f, qs = 0.f, qs2 = 0.f;
        #pragma unroll 4
        for (int k = 0; k < 16; ++k) {
            const float4 q  = qrow[part * 16 + k];
            const float4 pa = prow0[part * 16 + k];
            const float4 pb = prow1[part * 16 + k];
            cd0 = fmaf(pa.x, q.x, fmaf(pa.y, q.y, fmaf(pa.z, q.z, fmaf(pa.w, q.w, cd0))));
            cd1 = fmaf(pb.x, q.x, fmaf(pb.y, q.y, fmaf(pb.z, q.z, fmaf(pb.w, q.w, cd1))));
            qs += (q.x + q.y) + (q.z + q.w);
            qs2 = fmaf(q.x, q.x, fmaf(q.y, q.y, fmaf(q.z, q.z, fmaf(q.w, q.w, qs2))));
        }
        #pragma unroll
        for (int off = 1; off < 4; off <<= 1) {
            cd0 += __shfl_xor(cd0, off); cd1 += __shfl_xor(cd1, off);
            qs  += __shfl_xor(qs,  off); qs2 += __shfl_xor(qs2, off);
        }
        if (part == 0) {
            const float inv = 1.0f / NH;
            const float mu0 = (SP1_0 + qs) * inv;
            const float e0  = (SP2_0 + 2.0f * cd0 + qs2) * inv;
            lds_mu[0][j] = mu0;
            lds_rr[0][j] = __builtin_amdgcn_rsqf(e0 - mu0 * mu0 + LN_EPS);
            const float mu1 = (SP1_1 + qs) * inv;
            const float e1  = (SP2_1 + 2.0f * cd1 + qs2) * inv;
            lds_mu[1][j] = mu1;
            lds_rr[1][j] = __builtin_amdgcn_rsqf(e1 - mu1 * mu1 + LN_EPS);
        }
    }
    __syncthreads();

    // main loop: no cross-lane ops, no branches
    const float4 P0 = ((const float4*)lds_pt[0])[lane];
    const float4 P1 = ((const float4*)lds_pt[1])[lane];
    const float4 G  = ((const float4*)ge)[lane];
    const float4 Bg = ((const float4*)bge)[lane];
    const float4* Qb = (const float4*)(Qm + (size_t)b * NN * NH);
    float4 A0 = make_float4(0.f, 0.f, 0.f, 0.f);
    float4 A1 = make_float4(0.f, 0.f, 0.f, 0.f);
    #pragma unroll 4
    for (int jj = wave; jj < NN; jj += 4) {
        const float4 q = Qb[jj * (NH / 4) + lane];
        {
            const float wj = lds_w[0][jj], mu = lds_mu[0][jj], rr = lds_rr[0][jj];
            float h, u;
            h = P0.x + q.x; u = fmaf((h - mu) * rr, G.x, Bg.x); A0.x = fmaf(wj, gelu_fast(u), A0.x);
            h = P0.y + q.y; u = fmaf((h - mu) * rr, G.y, Bg.y); A0.y = fmaf(wj, gelu_fast(u), A0.y);
            h = P0.z + q.z; u = fmaf((h - mu) * rr, G.z, Bg.z); A0.z = fmaf(wj, gelu_fast(u), A0.z);
            h = P0.w + q.w; u = fmaf((h - mu) * rr, G.w, Bg.w); A0.w = fmaf(wj, gelu_fast(u), A0.w);
        }
        {
            const float wj = lds_w[1][jj], mu = lds_mu[1][jj], rr = lds_rr[1][jj];
            float h, u;
            h = P1.x + q.x; u = fmaf((h - mu) * rr, G.x, Bg.x); A1.x = fmaf(wj, gelu_fast(u), A1.x);
            h = P1.y + q.y; u = fmaf((h - mu) * rr, G.y, Bg.y); A1.y = fmaf(wj, gelu_fast(u), A1.y);
            h = P1.z + q.z; u = fmaf((h - mu) * rr, G.z, Bg.z); A1.z = fmaf(wj, gelu_fast(u), A1.z);
            h = P1.w + q.w; u = fmaf((h - mu) * rr, G.w, Bg.w); A1.w = fmaf(wj, gelu_fast(u), A1.w);
        }
    }

    ((float4*)&lds_s[wave][0][0])[lane] = A0;
    ((float4*)&lds_s[wave][1][0])[lane] = A1;
    __syncthreads();
    const float S0 = (lds_s[0][0][t] + lds_s[1][0][t]) + (lds_s[2][0][t] + lds_s[3][0][t]);
    const float S1 = (lds_s[0][1][t] + lds_s[1][1][t]) + (lds_s[2][1][t] + lds_s[3][1][t]);
    Sw[(size_t)r0 * NH + t]       = S0;
    Sw[(size_t)(r0 + 1) * NH + t] = S1;
    if (t < IBLK) {
        const float* wr = lds_w[t];
        float acc = 0.f;
        for (int k = 0; k < NN; ++k) acc += wr[k];
        wsumw[r0 + t] = acc;
    }
}

// ---------------- K3: node MLP, 8 rows per block ----------------
#define R3 8
__global__ __launch_bounds__(256) void k_node(
    const float* __restrict__ slots,
    const float* __restrict__ Sw, const float* __restrict__ wsumw,
    const float* __restrict__ We2, const float* __restrict__ be2,
    const float* __restrict__ Wn1, const float* __restrict__ bn1,
    const float* __restrict__ gn,  const float* __restrict__ bgn,
    const float* __restrict__ Wn2, const float* __restrict__ bn2,
    float* __restrict__ out)
{
    __shared__ float lds_x[R3][ND];
    __shared__ float lds_S[R3][NH];
    __shared__ float lds_m[R3][ND];
    __shared__ float lds_g[R3][NH];
    __shared__ float lds_mu[R3], lds_rr[R3];
    __shared__ float lds_redA[4][R3], lds_redB[4][R3];

    const int r0 = blockIdx.x * R3;
    const int t  = threadIdx.x;
    const int lane = t & 63;
    const int wave = t >> 6;
    const int c    = t & 127;
    const int half = t >> 7;

    #pragma unroll
    for (int r = 0; r < R3; ++r) {
        lds_S[r][t] = Sw[(size_t)(r0 + r) * NH + t];
        if (t < ND) lds_x[r][t] = slots[(size_t)(r0 + r) * ND + t];
    }
    __syncthreads();

    // messages = S @ We2 + wsum*be2 ; thread: channel c, 4 rows (half selects row group)
    {
        float acc[4];
        const float bb = be2[c];
        #pragma unroll
        for (int r = 0; r < 4; ++r) acc[r] = wsumw[r0 + half * 4 + r] * bb;
        for (int k = 0; k < NH; ++k) {
            const float w = We2[k * ND + c];
            #pragma unroll
            for (int r = 0; r < 4; ++r) acc[r] = fmaf(lds_S[half * 4 + r][k], w, acc[r]);
        }
        #pragma unroll
        for (int r = 0; r < 4; ++r) lds_m[half * 4 + r][c] = acc[r];
    }
    __syncthreads();

    // h1 = [x, m] @ Wn1 + bn1 ; thread: channel t, all 8 rows
    float h[R3];
    {
        const float bb = bn1[t];
        #pragma unroll
        for (int r = 0; r < R3; ++r) h[r] = bb;
        for (int k = 0; k < ND; ++k) {
            const float w = Wn1[k * NH + t];
            #pragma unroll
            for (int r = 0; r < R3; ++r) h[r] = fmaf(lds_x[r][k], w, h[r]);
        }
        for (int k = 0; k < ND; ++k) {
            const float w = Wn1[(ND + k) * NH + t];
            #pragma unroll
            for (int r = 0; r < R3; ++r) h[r] = fmaf(lds_m[r][k], w, h[r]);
        }
    }

    // LN stats per row across the 256 threads
    #pragma unroll
    for (int r = 0; r < R3; ++r) {
        float a = h[r], bsq = h[r] * h[r];
        #pragma unroll
        for (int off = 32; off; off >>= 1) { a += __shfl_xor(a, off); bsq += __shfl_xor(bsq, off); }
        if (lane == 0) { lds_redA[wave][r] = a; lds_redB[wave][r] = bsq; }
    }
    __syncthreads();
    if (t < R3) {
        const int r = t;
        const float S1 = (lds_redA[0][r] + lds_redA[1][r]) + (lds_redA[2][r] + lds_redA[3][r]);
        const float S2 = (lds_redB[0][r] + lds_redB[1][r]) + (lds_redB[2][r] + lds_redB[3][r]);
        const float mu = S1 * (1.0f / NH);
        const float var = S2 * (1.0f / NH) - mu * mu;
        lds_mu[r] = mu;
        lds_rr[r] = __builtin_amdgcn_rsqf(var + LN_EPS);
    }
    __syncthreads();
    {
        const float g = gn[t], bg = bgn[t];
        #pragma unroll
        for (int r = 0; r < R3; ++r)
            lds_g[r][t] = gelu_fast(fmaf((h[r] - lds_mu[r]) * lds_rr[r], g, bg));
    }
    __syncthreads();

    // delta = g1 @ Wn2 + bn2 ; out = x + delta
    {
        float acc[4];
        const float bb = bn2[c];
        #pragma unroll
        for (int r = 0; r < 4; ++r) acc[r] = bb;
        for (int k = 0; k < NH; ++k) {
            const float w = Wn2[k * ND + c];
            #pragma unroll
            for (int r = 0; r < 4; ++r) acc[r] = fmaf(lds_g[half * 4 + r][k], w, acc[r]);
        }
        #pragma unroll
        for (int r = 0; r < 4; ++r)
            out[(size_t)(r0 + half * 4 + r) * ND + c] = lds_x[half * 4 + r][c] + acc[r];
    }
}

extern "C" void kernel_launch(void* const* d_in, const int* in_sizes, int n_in,
                              void* d_out, int out_size, void* d_ws, size_t ws_size,
                              hipStream_t stream) {
    const float* slots = (const float*)d_in[0];
    const float* adj   = (const float*)d_in[1];
    const float* We1   = (const float*)d_in[2];
    const float* be1   = (const float*)d_in[3];
    const float* ge    = (const float*)d_in[4];
    const float* bge   = (const float*)d_in[5];
    const float* We2   = (const float*)d_in[6];
    const float* be2   = (const float*)d_in[7];
    const float* Wn1   = (const float*)d_in[8];
    const float* bn1   = (const float*)d_in[9];
    const float* gn    = (const float*)d_in[10];
    const float* bgn   = (const float*)d_in[11];
    const float* Wn2   = (const float*)d_in[12];
    const float* bn2   = (const float*)d_in[13];
    float* out = (float*)d_out;

    float* Ptw   = (float*)d_ws;                    // [2048,256]
    float* Qw    = Ptw + (size_t)NB * NN * NH;      // [2048,256]
    float* Sw    = Qw  + (size_t)NB * NN * NH;      // [2048,256]
    float* wsumw = Sw  + (size_t)NB * NN * NH;      // [2048]

    k_pq  <<<NB * NN / RP,   256, 0, stream>>>(slots, We1, be1, Ptw, Qw);
    k_msg <<<NB * NN / IBLK, 256, 0, stream>>>(adj, Ptw, Qw, ge, bge, Sw, wsumw);
    k_node<<<NB * NN / R3,   256, 0, stream>>>(slots, Sw, wsumw, We2, be2,
                                               Wn1, bn1, gn, bgn, Wn2, bn2, out);
}

// Round 3
// 63.304 us; speedup vs baseline: 1.5590x; 1.2616x over previous
//
#include <hip/hip_runtime.h>

#define NB 32
#define NN 64
#define ND 128
#define NH 256
#define LN_EPS 1e-5f
#define IBLK 4
#define RP 4

// Branchless erf-based exact GELU (A&S 7.1.26, |erf err| <= 1.5e-7)
__device__ __forceinline__ float gelu_fast(float x) {
    const float z  = fabsf(x) * 0.70710678118654752440f;
    const float t  = __builtin_amdgcn_rcpf(fmaf(0.3275911f, z, 1.0f));
    float p = fmaf(1.061405429f, t, -1.453152027f);
    p = fmaf(p, t, 1.421413741f);
    p = fmaf(p, t, -0.284496736f);
    p = fmaf(p, t, 0.254829592f);
    p = p * t;
    const float e  = __expf(-z * z);
    const float er = copysignf(fmaf(-p, e, 1.0f), x);
    const float sx = 0.5f * x;
    return fmaf(sx, er, sx);
}

// ---------------- K1: Pt = slots@We1_top + be1 ; Qm = slots@We1_bot ----------------
__global__ __launch_bounds__(256) void k_pq(const float* __restrict__ slots,
                                            const float* __restrict__ We1,
                                            const float* __restrict__ be1,
                                            float* __restrict__ Pt,
                                            float* __restrict__ Qm) {
    const int r0 = blockIdx.x * RP;
    const int t  = threadIdx.x;
    float pt[RP], qq[RP];
    const float bb = be1[t];
    #pragma unroll
    for (int r = 0; r < RP; ++r) { pt[r] = bb; qq[r] = 0.f; }
    const float* w1 = We1 + t;
    #pragma unroll 2
    for (int dc = 0; dc < ND / 4; ++dc) {
        float xs[RP][4];
        #pragma unroll
        for (int r = 0; r < RP; ++r) {
            const float4 x4 = ((const float4*)(slots + (size_t)(r0 + r) * ND))[dc];
            xs[r][0] = x4.x; xs[r][1] = x4.y; xs[r][2] = x4.z; xs[r][3] = x4.w;
        }
        #pragma unroll
        for (int i = 0; i < 4; ++i) {
            const int d = dc * 4 + i;
            const float wt  = w1[d * NH];
            const float wbt = w1[(ND + d) * NH];
            #pragma unroll
            for (int r = 0; r < RP; ++r) {
                pt[r] = fmaf(xs[r][i], wt,  pt[r]);
                qq[r] = fmaf(xs[r][i], wbt, qq[r]);
            }
        }
    }
    #pragma unroll
    for (int r = 0; r < RP; ++r) {
        Pt[(size_t)(r0 + r) * NH + t] = pt[r];
        Qm[(size_t)(r0 + r) * NH + t] = qq[r];
    }
}

// ---------------- K2: fused edge loop + node MLP, 4 rows per block ----------------
__global__ __launch_bounds__(256) void k_fused(
    const float* __restrict__ slots,
    const float* __restrict__ adj,
    const float* __restrict__ Pt,
    const float* __restrict__ Qm,
    const float* __restrict__ ge,  const float* __restrict__ bge,
    const float* __restrict__ We2, const float* __restrict__ be2,
    const float* __restrict__ Wn1, const float* __restrict__ bn1,
    const float* __restrict__ gn,  const float* __restrict__ bgn,
    const float* __restrict__ Wn2, const float* __restrict__ bn2,
    float* __restrict__ out)
{
    __shared__ float  lds_pt[IBLK][NH];        // 4KB
    __shared__ float  lds_x [IBLK][ND];        // 2KB
    __shared__ float4 lds_wmr[IBLK][NN];       // 4KB  {w, mu, rr, -}
    __shared__ float  lds_s [4][IBLK][NH];     // 16KB wave-partial S
    __shared__ float  lds_sf[IBLK][NH];        // 4KB
    __shared__ float  lds_nin[IBLK][2 * ND];   // 4KB
    __shared__ float  lds_g [IBLK][NH];        // 4KB
    __shared__ float  lds_redA[4][IBLK], lds_redB[4][IBLK];
    __shared__ float  lds_wsum[IBLK];
    __shared__ float  lds_mu[IBLK], lds_rr[IBLK];

    const int blk  = blockIdx.x;
    const int b    = blk >> 4;
    const int i0   = (blk & 15) * IBLK;
    const int r0   = b * NN + i0;
    const int t    = threadIdx.x;
    const int lane = t & 63;
    const int wave = t >> 6;
    const int c    = t & 127;
    const int rg   = t >> 7;

    // ---- phase 0: loads ----
    #pragma unroll
    for (int r = 0; r < IBLK; ++r)
        lds_pt[r][t] = Pt[(size_t)(r0 + r) * NH + t];
    lds_x[rg][c]     = slots[(size_t)(r0 + rg) * ND + c];
    lds_x[rg + 2][c] = slots[(size_t)(r0 + rg + 2) * ND + c];
    {
        float av = adj[(size_t)(r0 + wave) * NN + lane];
        if (lane == i0 + wave) av = 0.f;       // diagonal mask
        lds_wmr[wave][lane].x = av;
        float ws = av;
        #pragma unroll
        for (int off = 32; off; off >>= 1) ws += __shfl_xor(ws, off);
        if (lane == 0) lds_wsum[wave] = ws;
    }
    __syncthreads();

    // ---- phase 1: per-row P sums + C-dot prologue ----
    {
        float a[IBLK], bq[IBLK];
        #pragma unroll
        for (int r = 0; r < IBLK; ++r) { const float p = lds_pt[r][t]; a[r] = p; bq[r] = p * p; }
        #pragma unroll
        for (int off = 32; off; off >>= 1) {
            #pragma unroll
            for (int r = 0; r < IBLK; ++r) {
                a[r]  += __shfl_xor(a[r],  off);
                bq[r] += __shfl_xor(bq[r], off);
            }
        }
        if (lane == 0) {
            #pragma unroll
            for (int r = 0; r < IBLK; ++r) { lds_redA[wave][r] = a[r]; lds_redB[wave][r] = bq[r]; }
        }
    }
    const int jp   = t >> 2;
    const int part = t & 3;
    float cd[IBLK] = {0.f, 0.f, 0.f, 0.f};
    float qs = 0.f, qs2 = 0.f;
    {
        const float4* qrow = (const float4*)(Qm + ((size_t)b * NN + jp) * NH) + part * 16;
        #pragma unroll 4
        for (int k = 0; k < 16; ++k) {
            const int kk = (k + part * 4) & 15;     // stagger to avoid LDS bank pileup
            const float4 q = qrow[kk];
            qs  += (q.x + q.y) + (q.z + q.w);
            qs2  = fmaf(q.x, q.x, fmaf(q.y, q.y, fmaf(q.z, q.z, fmaf(q.w, q.w, qs2))));
            #pragma unroll
            for (int r = 0; r < IBLK; ++r) {
                const float4 p = ((const float4*)lds_pt[r])[part * 16 + kk];
                cd[r] = fmaf(p.x, q.x, fmaf(p.y, q.y, fmaf(p.z, q.z, fmaf(p.w, q.w, cd[r]))));
            }
        }
        #pragma unroll
        for (int off = 1; off < 4; off <<= 1) {
            qs += __shfl_xor(qs, off); qs2 += __shfl_xor(qs2, off);
            #pragma unroll
            for (int r = 0; r < IBLK; ++r) cd[r] += __shfl_xor(cd[r], off);
        }
    }
    __syncthreads();
    if (part == 0) {
        const float inv = 1.0f / NH;
        #pragma unroll
        for (int r = 0; r < IBLK; ++r) {
            const float SP1 = (lds_redA[0][r] + lds_redA[1][r]) + (lds_redA[2][r] + lds_redA[3][r]);
            const float SP2 = (lds_redB[0][r] + lds_redB[1][r]) + (lds_redB[2][r] + lds_redB[3][r]);
            const float mu  = (SP1 + qs) * inv;
            const float e2  = (SP2 + 2.f * cd[r] + qs2) * inv;
            lds_wmr[r][jp].y = mu;
            lds_wmr[r][jp].z = __builtin_amdgcn_rsqf(e2 - mu * mu + LN_EPS);
        }
    }
    __syncthreads();

    // ---- phase 2: edge main loop (no cross-lane, no branches) ----
    float4 P[IBLK], A[IBLK];
    #pragma unroll
    for (int r = 0; r < IBLK; ++r) {
        P[r] = ((const float4*)lds_pt[r])[lane];
        A[r] = make_float4(0.f, 0.f, 0.f, 0.f);
    }
    const float4 G  = ((const float4*)ge)[lane];
    const float4 Bg = ((const float4*)bge)[lane];
    const float4* Qb = (const float4*)(Qm + (size_t)b * NN * NH);
    #pragma unroll 2
    for (int jj = wave; jj < NN; jj += 4) {
        const float4 q = Qb[jj * (NH / 4) + lane];
        #pragma unroll
        for (int r = 0; r < IBLK; ++r) {
            const float4 wmr = lds_wmr[r][jj];
            const float wj = wmr.x, mu = wmr.y, rr = wmr.z;
            float h, u;
            h = P[r].x + q.x; u = fmaf((h - mu) * rr, G.x, Bg.x); A[r].x = fmaf(wj, gelu_fast(u), A[r].x);
            h = P[r].y + q.y; u = fmaf((h - mu) * rr, G.y, Bg.y); A[r].y = fmaf(wj, gelu_fast(u), A[r].y);
            h = P[r].z + q.z; u = fmaf((h - mu) * rr, G.z, Bg.z); A[r].z = fmaf(wj, gelu_fast(u), A[r].z);
            h = P[r].w + q.w; u = fmaf((h - mu) * rr, G.w, Bg.w); A[r].w = fmaf(wj, gelu_fast(u), A[r].w);
        }
    }
    #pragma unroll
    for (int r = 0; r < IBLK; ++r)
        ((float4*)&lds_s[wave][r][0])[lane] = A[r];
    __syncthreads();
    #pragma unroll
    for (int r = 0; r < IBLK; ++r)
        lds_sf[r][t] = (lds_s[0][r][t] + lds_s[1][r][t]) + (lds_s[2][r][t] + lds_s[3][r][t]);
    __syncthreads();

    // ---- phase 3: messages = S @ We2 + wsum*be2 -> nin ----
    {
        const int ra = rg, rb = rg + 2;
        float ma = lds_wsum[ra] * be2[c];
        float mb = lds_wsum[rb] * be2[c];
        const float* w2 = We2 + c;
        #pragma unroll 2
        for (int kc = 0; kc < NH / 4; ++kc) {
            const float4 sa = ((const float4*)lds_sf[ra])[kc];
            const float4 sb = ((const float4*)lds_sf[rb])[kc];
            const float w0 = w2[(4 * kc + 0) * ND];
            const float wA = w2[(4 * kc + 1) * ND];
            const float wB = w2[(4 * kc + 2) * ND];
            const float wC = w2[(4 * kc + 3) * ND];
            ma = fmaf(sa.x, w0, fmaf(sa.y, wA, fmaf(sa.z, wB, fmaf(sa.w, wC, ma))));
            mb = fmaf(sb.x, w0, fmaf(sb.y, wA, fmaf(sb.z, wB, fmaf(sb.w, wC, mb))));
        }
        lds_nin[ra][c] = lds_x[ra][c];  lds_nin[ra][ND + c] = ma;
        lds_nin[rb][c] = lds_x[rb][c];  lds_nin[rb][ND + c] = mb;
    }
    __syncthreads();

    // ---- phase 4: h1 = nin @ Wn1 + bn1 ; LN ; GELU ----
    float h[IBLK];
    {
        const float bb = bn1[t];
        #pragma unroll
        for (int r = 0; r < IBLK; ++r) h[r] = bb;
        const float* wn1 = Wn1 + t;
        #pragma unroll 2
        for (int kc = 0; kc < (2 * ND) / 4; ++kc) {
            float4 n4[IBLK];
            #pragma unroll
            for (int r = 0; r < IBLK; ++r) n4[r] = ((const float4*)lds_nin[r])[kc];
            const float w0 = wn1[(4 * kc + 0) * NH];
            const float wA = wn1[(4 * kc + 1) * NH];
            const float wB = wn1[(4 * kc + 2) * NH];
            const float wC = wn1[(4 * kc + 3) * NH];
            #pragma unroll
            for (int r = 0; r < IBLK; ++r)
                h[r] = fmaf(n4[r].x, w0, fmaf(n4[r].y, wA, fmaf(n4[r].z, wB, fmaf(n4[r].w, wC, h[r]))));
        }
    }
    {
        float a2[IBLK], b2[IBLK];
        #pragma unroll
        for (int r = 0; r < IBLK; ++r) { a2[r] = h[r]; b2[r] = h[r] * h[r]; }
        #pragma unroll
        for (int off = 32; off; off >>= 1) {
            #pragma unroll
            for (int r = 0; r < IBLK; ++r) {
                a2[r] += __shfl_xor(a2[r], off);
                b2[r] += __shfl_xor(b2[r], off);
            }
        }
        if (lane == 0) {
            #pragma unroll
            for (int r = 0; r < IBLK; ++r) { lds_redA[wave][r] = a2[r]; lds_redB[wave][r] = b2[r]; }
        }
    }
    __syncthreads();
    if (t < IBLK) {
        const float S1 = (lds_redA[0][t] + lds_redA[1][t]) + (lds_redA[2][t] + lds_redA[3][t]);
        const float S2 = (lds_redB[0][t] + lds_redB[1][t]) + (lds_redB[2][t] + lds_redB[3][t]);
        const float mu  = S1 * (1.0f / NH);
        const float var = S2 * (1.0f / NH) - mu * mu;
        lds_mu[t] = mu;
        lds_rr[t] = __builtin_amdgcn_rsqf(var + LN_EPS);
    }
    __syncthreads();
    {
        const float g = gn[t], bg = bgn[t];
        #pragma unroll
        for (int r = 0; r < IBLK; ++r)
            lds_g[r][t] = gelu_fast(fmaf((h[r] - lds_mu[r]) * lds_rr[r], g, bg));
    }
    __syncthreads();

    // ---- phase 5: delta = g @ Wn2 + bn2 ; out = x + delta ----
    {
        const int ra = rg, rb = rg + 2;
        float da = bn2[c], db = bn2[c];
        const float* w2 = Wn2 + c;
        #pragma unroll 2
        for (int kc = 0; kc < NH / 4; ++kc) {
            const float4 ga = ((const float4*)lds_g[ra])[kc];
            const float4 gb = ((const float4*)lds_g[rb])[kc];
            const float w0 = w2[(4 * kc + 0) * ND];
            const float wA = w2[(4 * kc + 1) * ND];
            const float wB = w2[(4 * kc + 2) * ND];
            const float wC = w2[(4 * kc + 3) * ND];
            da = fmaf(ga.x, w0, fmaf(ga.y, wA, fmaf(ga.z, wB, fmaf(ga.w, wC, da))));
            db = fmaf(gb.x, w0, fmaf(gb.y, wA, fmaf(gb.z, wB, fmaf(gb.w, wC, db))));
        }
        out[(size_t)(r0 + ra) * ND + c] = lds_x[ra][c] + da;
        out[(size_t)(r0 + rb) * ND + c] = lds_x[rb][c] + db;
    }
}

extern "C" void kernel_launch(void* const* d_in, const int* in_sizes, int n_in,
                              void* d_out, int out_size, void* d_ws, size_t ws_size,
                              hipStream_t stream) {
    const float* slots = (const float*)d_in[0];
    const float* adj   = (const float*)d_in[1];
    const float* We1   = (const float*)d_in[2];
    const float* be1   = (const float*)d_in[3];
    const float* ge    = (const float*)d_in[4];
    const float* bge   = (const float*)d_in[5];
    const float* We2   = (const float*)d_in[6];
    const float* be2   = (const float*)d_in[7];
    const float* Wn1   = (const float*)d_in[8];
    const float* bn1   = (const float*)d_in[9];
    const float* gn    = (const float*)d_in[10];
    const float* bgn   = (const float*)d_in[11];
    const float* Wn2   = (const float*)d_in[12];
    const float* bn2   = (const float*)d_in[13];
    float* out = (float*)d_out;

    float* Ptw = (float*)d_ws;                  // [2048,256]
    float* Qw  = Ptw + (size_t)NB * NN * NH;    // [2048,256]

    k_pq   <<<NB * NN / RP,   256, 0, stream>>>(slots, We1, be1, Ptw, Qw);
    k_fused<<<NB * NN / IBLK, 256, 0, stream>>>(slots, adj, Ptw, Qw, ge, bge, We2, be2,
                                                Wn1, bn1, gn, bgn, Wn2, bn2, out);
}